// Round 4
// baseline (396.407 us; speedup 1.0000x reference)
//
#include <hip/hip_runtime.h>
#include <hip/hip_bf16.h>

#define NN 256
#define MM 128
#define DS 384
#define DP 128
#define CC 22
#define C2 484

#define OUT_EI  (NN*NN*C2)
#define OUT_LOG (OUT_EI + NN*CC)

// compact zE: per j, 22 c-rows x 48 B (24 d-slots, d22/23 stay zero)
#define ZSTRJ 1056
#define ZE_END (16*ZSTRJ + 512)    // 17408 (512B tail pad for cp1 row-overflow reads)
#define LDS_TOTAL (ZE_END + 2048)  // 19456 (+ msa_s 16x128 bytes)

typedef __attribute__((ext_vector_type(8))) short short8;
typedef __attribute__((ext_vector_type(4))) float f32x4;

__device__ __forceinline__ unsigned f2bf(float x) {
  unsigned u = __float_as_uint(x);
  return (u + 0x7FFFu + ((u >> 16) & 1u)) >> 16;
}

// ---------------------------------------------------------------------------
// prep: msa transpose -> uchar [256][128]; blocks<124 also pack w3 bf16 frags
// frag(kt,ct): lane l, elem e = w3[kt*32+(l>>4)*8+e][ct*16+(l&15)]
// ---------------------------------------------------------------------------
__global__ __launch_bounds__(128) void k_prep(
    const float* __restrict__ w3, const int* __restrict__ msa,
    int4* __restrict__ w3f, unsigned char* __restrict__ mt)
{
  int b = blockIdx.x, t = threadIdx.x;
  mt[b * MM + t] = (unsigned char)msa[t * NN + b];
  if (b < 124 && t < 64) {
    int ct = b % 31, kt = b / 31, l = t;
    int c = ct * 16 + (l & 15);
    int kb = kt * 32 + (l >> 4) * 8;
    unsigned v[8];
#pragma unroll
    for (int e = 0; e < 8; ++e)
      v[e] = (c < C2) ? f2bf(w3[(kb + e) * C2 + c]) : 0u;
    int4 pk;
    pk.x = (int)(v[0] | (v[1] << 16));
    pk.y = (int)(v[2] | (v[3] << 16));
    pk.z = (int)(v[4] | (v[5] << 16));
    pk.w = (int)(v[6] | (v[7] << 16));
    w3f[(kt * 31 + ct) * 64 + l] = pk;
  }
}

// ---------------------------------------------------------------------------
// single branch -> ei[n,:]; also zeroes logits[:, n, :]
// ---------------------------------------------------------------------------
__global__ __launch_bounds__(384) void k_single(
    const float* __restrict__ single, const float* __restrict__ w1,
    const float* __restrict__ b1, const float* __restrict__ g1,
    const float* __restrict__ be1, const float* __restrict__ w2,
    const float* __restrict__ b2, float* __restrict__ out_ei,
    float* __restrict__ out_log)
{
  __shared__ float srow[DS];
  __shared__ float hlx[DS];
  __shared__ float part[16 * CC];
  __shared__ float wred[8], wredq[8], mur[2];
  int n = blockIdx.x, t = threadIdx.x;
  srow[t] = single[n * DS + t];
  for (int idx = t; idx < MM * CC; idx += 384) {
    int m = idx / CC, c = idx - m * CC;
    out_log[(m * NN + n) * CC + c] = 0.f;
  }
  __syncthreads();
  float acc = b1[t];
#pragma unroll 8
  for (int d = 0; d < DS; ++d) acc = fmaf(srow[d], w1[d * DS + t], acc);
  float hv = 0.5f * acc * (1.0f + erff(acc * 0.70710678118654752f));
  float s = hv, q = hv * hv;
#pragma unroll
  for (int off = 32; off; off >>= 1) { s += __shfl_xor(s, off); q += __shfl_xor(q, off); }
  if ((t & 63) == 0) { wred[t >> 6] = s; wredq[t >> 6] = q; }
  __syncthreads();
  if (t == 0) {
    float S = 0.f, Q = 0.f;
    for (int w = 0; w < 6; ++w) { S += wred[w]; Q += wredq[w]; }
    float mu = S / (float)DS;
    mur[0] = mu; mur[1] = rsqrtf(Q / (float)DS - mu * mu + 1e-5f);
  }
  __syncthreads();
  hlx[t] = (hv - mur[0]) * mur[1] * g1[t] + be1[t];
  __syncthreads();
  if (t < 352) {
    int g = t / CC, c = t - g * CC;
    float p = 0.f;
#pragma unroll
    for (int k = g * 24; k < g * 24 + 24; ++k) p = fmaf(hlx[k], w2[k * CC + c], p);
    part[t] = p;
  }
  __syncthreads();
  if (t < CC) {
    float sm = b2[t];
#pragma unroll
    for (int g = 0; g < 16; ++g) sm += part[g * CC + t];
    out_ei[n * CC + t] = sm;
  }
}

// ---------------------------------------------------------------------------
// Fused pair+coevolution. grid (256 i, 8 jq), block 256 (4 waves).
// Per chunk of 16 j: LN->zln bf16 (overlaid on zE); A-frags to regs; MFMA
// zln@w3f -> eij f32 global + compact bf16 zE; MFMA zE vs in-reg one-hot.
// Epilogue: atomicAdd hi (+ei on jq==0) into pre-zeroed logits.
// ---------------------------------------------------------------------------
__global__ __launch_bounds__(256, 6) void k_fused(
    const float* __restrict__ pair, const unsigned char* __restrict__ msa_tb,
    const float* __restrict__ g2, const float* __restrict__ be2,
    const float* __restrict__ b3, const int4* __restrict__ w3f,
    const float* __restrict__ ei,
    float* __restrict__ out_eij, float* __restrict__ out_log)
{
  __shared__ __align__(16) char smem[LDS_TOTAL];
  unsigned char* msa_s = (unsigned char*)(smem + ZE_END);

  const int i = blockIdx.x, jq = blockIdx.y;
  const int t = threadIdx.x;
  const int w = t >> 6, l = t & 63;
  const int lr = l & 15, lg = l >> 4;

  // zero LDS once (zE pad slots d=22,23 must stay 0.0 bf16; never written)
  for (int idx = t; idx < LDS_TOTAL / 4; idx += 256) ((unsigned*)smem)[idx] = 0u;

  f32x4 acc[2][2];
#pragma unroll
  for (int a_ = 0; a_ < 2; ++a_)
#pragma unroll
    for (int b_ = 0; b_ < 2; ++b_) acc[a_][b_] = (f32x4){0.f, 0.f, 0.f, 0.f};

  const float2 g2v = ((const float2*)g2)[l];
  const float2 bev = ((const float2*)be2)[l];
  const short8* w3fv = (const short8*)w3f;
  __syncthreads();

  for (int ch = 0; ch < 2; ++ch) {
    const int j0 = jq * 32 + ch * 16;

    // ---- phase1: zsym -> LN -> bf16 zln (wave w: rows w*4..w*4+3) ----
#pragma unroll
    for (int it = 0; it < 4; ++it) {
      int jl = w * 4 + it;
      int j = j0 + jl;
      float2 a = ((const float2*)(pair + (i * NN + j) * DP))[l];
      float2 b = ((const float2*)(pair + (j * NN + i) * DP))[l];
      float zx = 0.5f * (a.x + b.x), zy = 0.5f * (a.y + b.y);
      float s = zx + zy, q = zx * zx + zy * zy;
#pragma unroll
      for (int off = 32; off; off >>= 1) { s += __shfl_xor(s, off); q += __shfl_xor(q, off); }
      float mu = s * (1.f / 128.f);
      float rs = rsqrtf(q * (1.f / 128.f) - mu * mu + 1e-5f);
      float nx = (zx - mu) * rs * g2v.x + bev.x;
      float ny = (zy - mu) * rs * g2v.y + bev.y;
      unsigned pk = f2bf(nx) | (f2bf(ny) << 16);
      int blk = (l >> 2) ^ jl;
      *(unsigned*)(smem + jl * 256 + blk * 16 + (l & 3) * 4) = pk;
    }
    // stage msa chunk (16 j x 128 m bytes, contiguous)
    ((uint2*)msa_s)[t] = ((const uint2*)(msa_tb + j0 * MM))[t];
    __syncthreads();

    // ---- A-fragments (same 16-j tile for all waves) ----
    short8 afr[4];
#pragma unroll
    for (int kt = 0; kt < 4; ++kt)
      afr[kt] = *(const short8*)(smem + lr * 256 + (((kt * 4 + lg) ^ lr) * 16));
    __syncthreads();   // zln consumed; zE overlay writes may begin

    // ---- phase2: MFMA zln @ w3f -> eij (global f32 + compact bf16 zE) ----
    for (int ct = w; ct < 31; ct += 4) {
      short8 bf0 = w3fv[(0 * 31 + ct) * 64 + l];
      short8 bf1 = w3fv[(1 * 31 + ct) * 64 + l];
      short8 bf2 = w3fv[(2 * 31 + ct) * 64 + l];
      short8 bf3 = w3fv[(3 * 31 + ct) * 64 + l];
      f32x4 cc2 = {0.f, 0.f, 0.f, 0.f};
      cc2 = __builtin_amdgcn_mfma_f32_16x16x32_bf16(afr[0], bf0, cc2, 0, 0, 0);
      cc2 = __builtin_amdgcn_mfma_f32_16x16x32_bf16(afr[1], bf1, cc2, 0, 0, 0);
      cc2 = __builtin_amdgcn_mfma_f32_16x16x32_bf16(afr[2], bf2, cc2, 0, 0, 0);
      cc2 = __builtin_amdgcn_mfma_f32_16x16x32_bf16(afr[3], bf3, cc2, 0, 0, 0);
      int cflat = ct * 16 + lr;
      if (cflat < C2) {
        float bias = b3[cflat];
        int cdiv = cflat / CC;
        int dd = cflat - cdiv * CC;
#pragma unroll
        for (int r = 0; r < 4; ++r) {
          int jl = lg * 4 + r, j = j0 + jl;
          float v = fmaxf(cc2[r] + bias, 0.f);
          if (j == i) v = 0.f;
          out_eij[(i * NN + j) * C2 + cflat] = v;
          *(unsigned short*)(smem + jl * ZSTRJ + cdiv * 48 + dd * 2) = (unsigned short)f2bf(v);
        }
      }
    }
    __syncthreads();

    // ---- phase3: coevolution MFMA (wave w: m-tiles w and w+4) ----
#pragma unroll 4
    for (int jj = 0; jj < 16; ++jj) {
      int s0 = msa_s[jj * 128 + w * 16 + lr];
      int s1 = msa_s[jj * 128 + (w + 4) * 16 + lr];
      union { short8 s8; unsigned u[4]; } b0, b1;
      {
        int rel = s0 - lg * 8;
        unsigned hval = (s0 != 21 && ((unsigned)rel) < 8u) ? (0x3F80u << ((rel & 1) << 4)) : 0u;
        int word = rel >> 1;
        b0.u[0] = (word == 0) ? hval : 0u;
        b0.u[1] = (word == 1) ? hval : 0u;
        b0.u[2] = (word == 2) ? hval : 0u;
        b0.u[3] = (word == 3) ? hval : 0u;
      }
      {
        int rel = s1 - lg * 8;
        unsigned hval = (s1 != 21 && ((unsigned)rel) < 8u) ? (0x3F80u << ((rel & 1) << 4)) : 0u;
        int word = rel >> 1;
        b1.u[0] = (word == 0) ? hval : 0u;
        b1.u[1] = (word == 1) ? hval : 0u;
        b1.u[2] = (word == 2) ? hval : 0u;
        b1.u[3] = (word == 3) ? hval : 0u;
      }
#pragma unroll
      for (int cp = 0; cp < 2; ++cp) {
        // rows c>=22 of cp=1 read adjacent-j data: finite, lands in discarded
        // output rows. d 24..31 (lg==3) overflow next c-row: one-hot B is 0
        // there (s<=20 => only d<=21 nonzero), so contributes 0.
        short8 af = *(const short8*)(smem + jj * ZSTRJ + (cp * 16 + lr) * 48 + lg * 16);
        acc[0][cp] = __builtin_amdgcn_mfma_f32_16x16x32_bf16(af, b0.s8, acc[0][cp], 0, 0, 0);
        acc[1][cp] = __builtin_amdgcn_mfma_f32_16x16x32_bf16(af, b1.s8, acc[1][cp], 0, 0, 0);
      }
    }
    __syncthreads();   // zE/zln reuse next chunk
  }

  // ---- epilogue: atomicAdd hi (+ ei on jq==0) ----
#pragma unroll
  for (int mt = 0; mt < 2; ++mt) {
    int m = (mt * 4 + w) * 16 + lr;
#pragma unroll
    for (int cp = 0; cp < 2; ++cp) {
#pragma unroll
      for (int r = 0; r < 4; ++r) {
        int c = cp * 16 + lg * 4 + r;
        if (c < CC) {
          float add = acc[mt][cp][r] + (jq == 0 ? ei[i * CC + c] : 0.f);
          atomicAdd(&out_log[(m * NN + i) * CC + c], add);
        }
      }
    }
  }
}

// ---------------------------------------------------------------------------
extern "C" void kernel_launch(void* const* d_in, const int* in_sizes, int n_in,
                              void* d_out, int out_size, void* d_ws, size_t ws_size,
                              hipStream_t stream) {
  const float* single = (const float*)d_in[0];
  const float* pairp  = (const float*)d_in[1];
  const int*   msa    = (const int*)d_in[2];
  const float* w1  = (const float*)d_in[3];
  const float* b1  = (const float*)d_in[4];
  const float* g1  = (const float*)d_in[5];
  const float* be1 = (const float*)d_in[6];
  const float* w2  = (const float*)d_in[7];
  const float* b2  = (const float*)d_in[8];
  const float* g2  = (const float*)d_in[9];
  const float* be2 = (const float*)d_in[10];
  const float* w3  = (const float*)d_in[11];
  const float* b3  = (const float*)d_in[12];

  float* out = (float*)d_out;
  float* out_eij = out;
  float* out_ei  = out + OUT_EI;
  float* out_log = out + OUT_LOG;

  int4* w3f = (int4*)d_ws;                                   // 124 KB
  unsigned char* msa_tb = (unsigned char*)d_ws + 131072;     // 32 KB

  hipLaunchKernelGGL(k_prep, dim3(NN), dim3(128), 0, stream, w3, msa, w3f, msa_tb);
  hipLaunchKernelGGL(k_single, dim3(NN), dim3(384), 0, stream,
                     single, w1, b1, g1, be1, w2, b2, out_ei, out_log);
  hipLaunchKernelGGL(k_fused, dim3(256, 8), dim3(256), 0, stream,
                     pairp, msa_tb, g2, be2, b3, (const int4*)w3f,
                     out_ei, out_eij, out_log);
}

// Round 7
// 265.613 us; speedup vs baseline: 1.4924x; 1.4924x over previous
//
#include <hip/hip_runtime.h>
#include <hip/hip_bf16.h>

#define NN 256
#define MM 128
#define DS 384
#define DP 128
#define CC 22
#define C2 484

#define OUT_EI  (NN*NN*C2)
#define OUT_LOG (OUT_EI + NN*CC)

// compact zE: per j, 22 c-rows x 48 B (24 d-slots, d22/23 stay zero)
#define ZSTRJ 1056
#define ZE_BYTES (32*ZSTRJ)          // 33792 (32 j rows)
#define ZE_END (ZE_BYTES + 512)      // 34304 (tail pad for cp1 row-overflow reads)
#define LDS_TOTAL (ZE_END + 4096)    // 38400 (+ msa_s 32x128 bytes)

typedef __attribute__((ext_vector_type(8))) short short8;
typedef __attribute__((ext_vector_type(4))) float f32x4;

__device__ __forceinline__ unsigned f2bf(float x) {
  unsigned u = __float_as_uint(x);
  return (u + 0x7FFFu + ((u >> 16) & 1u)) >> 16;
}

// ---------------------------------------------------------------------------
// prep: msa transpose -> uchar [256][128]; blocks<124 also pack w3 bf16 frags
// frag(kt,ct): lane l, elem e = w3[kt*32+(l>>4)*8+e][ct*16+(l&15)]   (R3-verbatim)
// ---------------------------------------------------------------------------
__global__ __launch_bounds__(128) void k_prep(
    const float* __restrict__ w3, const int* __restrict__ msa,
    int4* __restrict__ w3f, unsigned char* __restrict__ mt)
{
  int b = blockIdx.x, t = threadIdx.x;
  mt[b * MM + t] = (unsigned char)msa[t * NN + b];
  if (b < 124 && t < 64) {
    int ct = b % 31, kt = b / 31, l = t;
    int c = ct * 16 + (l & 15);
    int kb = kt * 32 + (l >> 4) * 8;
    unsigned v[8];
#pragma unroll
    for (int e = 0; e < 8; ++e)
      v[e] = (c < C2) ? f2bf(w3[(kb + e) * C2 + c]) : 0u;
    int4 pk;
    pk.x = (int)(v[0] | (v[1] << 16));
    pk.y = (int)(v[2] | (v[3] << 16));
    pk.z = (int)(v[4] | (v[5] << 16));
    pk.w = (int)(v[6] | (v[7] << 16));
    w3f[(kt * 31 + ct) * 64 + l] = pk;
  }
}

// ---------------------------------------------------------------------------
// single branch -> ei[n,:]; also zeroes logits[:, n, :]   (R3-verbatim)
// ---------------------------------------------------------------------------
__global__ __launch_bounds__(384) void k_single(
    const float* __restrict__ single, const float* __restrict__ w1,
    const float* __restrict__ b1, const float* __restrict__ g1,
    const float* __restrict__ be1, const float* __restrict__ w2,
    const float* __restrict__ b2, float* __restrict__ out_ei,
    float* __restrict__ out_log)
{
  __shared__ float srow[DS];
  __shared__ float hlx[DS];
  __shared__ float part[16 * CC];
  __shared__ float wred[8], wredq[8], mur[2];
  int n = blockIdx.x, t = threadIdx.x;
  srow[t] = single[n * DS + t];
  for (int idx = t; idx < MM * CC; idx += 384) {
    int m = idx / CC, c = idx - m * CC;
    out_log[(m * NN + n) * CC + c] = 0.f;
  }
  __syncthreads();
  float acc = b1[t];
#pragma unroll 8
  for (int d = 0; d < DS; ++d) acc = fmaf(srow[d], w1[d * DS + t], acc);
  float hv = 0.5f * acc * (1.0f + erff(acc * 0.70710678118654752f));
  float s = hv, q = hv * hv;
#pragma unroll
  for (int off = 32; off; off >>= 1) { s += __shfl_xor(s, off); q += __shfl_xor(q, off); }
  if ((t & 63) == 0) { wred[t >> 6] = s; wredq[t >> 6] = q; }
  __syncthreads();
  if (t == 0) {
    float S = 0.f, Q = 0.f;
    for (int w = 0; w < 6; ++w) { S += wred[w]; Q += wredq[w]; }
    float mu = S / (float)DS;
    mur[0] = mu; mur[1] = rsqrtf(Q / (float)DS - mu * mu + 1e-5f);
  }
  __syncthreads();
  hlx[t] = (hv - mur[0]) * mur[1] * g1[t] + be1[t];
  __syncthreads();
  if (t < 352) {
    int g = t / CC, c = t - g * CC;
    float p = 0.f;
#pragma unroll
    for (int k = g * 24; k < g * 24 + 24; ++k) p = fmaf(hlx[k], w2[k * CC + c], p);
    part[t] = p;
  }
  __syncthreads();
  if (t < CC) {
    float sm = b2[t];
#pragma unroll
    for (int g = 0; g < 16; ++g) sm += part[g * CC + t];
    out_ei[n * CC + t] = sm;
  }
}

// ---------------------------------------------------------------------------
// Fused pair+coevolution (R3 structure, compact zE). grid (256 i, 2 jh),
// block 512 (8 waves), LDS 38.4 KB. Per chunk of 32 j:
//   phase1: zsym -> LN -> bf16 zln (overlaid at smem[0..8K), swizzled)
//   afr:    A-fragments for rows 0-15 (a0) and 16-31 (a1) into regs
//   phase2: MFMA zln@w3f -> +b3, relu, diag0 -> eij global + compact bf16 zE
//   phase3: MFMA zE vs in-register one-hot(msa) -> acc (wave w = m-tile w)
// Epilogue: atomicAdd hi (+ei on jh==0) into pre-zeroed logits (2-way).
// ---------------------------------------------------------------------------
__global__ __launch_bounds__(512, 4) void k_fused(
    const float* __restrict__ pair, const unsigned char* __restrict__ msa_tb,
    const float* __restrict__ g2, const float* __restrict__ be2,
    const float* __restrict__ b3, const int4* __restrict__ w3f,
    const float* __restrict__ ei,
    float* __restrict__ out_eij, float* __restrict__ out_log)
{
  __shared__ __align__(16) char smem[LDS_TOTAL];
  unsigned char* msa_s = (unsigned char*)(smem + ZE_END);

  const int i = blockIdx.x, jh = blockIdx.y;
  const int t = threadIdx.x;
  const int w = t >> 6, l = t & 63;
  const int lr = l & 15, lg = l >> 4;

  // zero zE + pad once (d=22,23 slots and tail pad must stay 0.0 bf16)
  for (int idx = t; idx < LDS_TOTAL / 4; idx += 512) ((unsigned*)smem)[idx] = 0u;

  f32x4 acc[2];
  acc[0] = (f32x4){0.f, 0.f, 0.f, 0.f};
  acc[1] = (f32x4){0.f, 0.f, 0.f, 0.f};

  const float2 g2v = ((const float2*)g2)[l];
  const float2 bev = ((const float2*)be2)[l];
  const short8* w3fv = (const short8*)w3f;
  __syncthreads();

  for (int ch = 0; ch < 4; ++ch) {
    const int j0 = jh * 128 + ch * 32;

    // ---- phase1: zsym -> LN -> bf16 zln (wave w: rows w*4..w*4+3) ----
#pragma unroll
    for (int it = 0; it < 4; ++it) {
      int jl = w * 4 + it;
      int j = j0 + jl;
      float2 a = ((const float2*)(pair + (i * NN + j) * DP))[l];
      float2 b = ((const float2*)(pair + (j * NN + i) * DP))[l];
      float zx = 0.5f * (a.x + b.x), zy = 0.5f * (a.y + b.y);
      float s = zx + zy, q = zx * zx + zy * zy;
#pragma unroll
      for (int off = 32; off; off >>= 1) { s += __shfl_xor(s, off); q += __shfl_xor(q, off); }
      float mu = s * (1.f / 128.f);
      float rs = rsqrtf(q * (1.f / 128.f) - mu * mu + 1e-5f);
      float nx = (zx - mu) * rs * g2v.x + bev.x;
      float ny = (zy - mu) * rs * g2v.y + bev.y;
      unsigned pk = f2bf(nx) | (f2bf(ny) << 16);
      int blk = (l >> 2) ^ (jl & 15);
      *(unsigned*)(smem + jl * 256 + blk * 16 + (l & 3) * 4) = pk;
    }
    // stage msa chunk (32 j x 128 m bytes, contiguous)
    ((uint2*)msa_s)[t] = ((const uint2*)(msa_tb + j0 * MM))[t];
    __syncthreads();

    // ---- A-fragments: rows 0-15 (a0), rows 16-31 (a1) ----
    short8 a0[4], a1[4];
#pragma unroll
    for (int kt = 0; kt < 4; ++kt) {
      a0[kt] = *(const short8*)(smem + lr * 256 + (((kt * 4 + lg) ^ lr) * 16));
      a1[kt] = *(const short8*)(smem + (16 + lr) * 256 + (((kt * 4 + lg) ^ lr) * 16));
    }
    __syncthreads();   // zln dead; zE overlay writes may begin

    // ---- phase2: MFMA zln @ w3f -> eij (global f32 + compact bf16 zE) ----
    for (int ct = w; ct < 31; ct += 8) {
      short8 bf0 = w3fv[(0 * 31 + ct) * 64 + l];
      short8 bf1 = w3fv[(1 * 31 + ct) * 64 + l];
      short8 bf2 = w3fv[(2 * 31 + ct) * 64 + l];
      short8 bf3 = w3fv[(3 * 31 + ct) * 64 + l];
      f32x4 c0 = {0.f, 0.f, 0.f, 0.f}, c1 = {0.f, 0.f, 0.f, 0.f};
      c0 = __builtin_amdgcn_mfma_f32_16x16x32_bf16(a0[0], bf0, c0, 0, 0, 0);
      c0 = __builtin_amdgcn_mfma_f32_16x16x32_bf16(a0[1], bf1, c0, 0, 0, 0);
      c0 = __builtin_amdgcn_mfma_f32_16x16x32_bf16(a0[2], bf2, c0, 0, 0, 0);
      c0 = __builtin_amdgcn_mfma_f32_16x16x32_bf16(a0[3], bf3, c0, 0, 0, 0);
      c1 = __builtin_amdgcn_mfma_f32_16x16x32_bf16(a1[0], bf0, c1, 0, 0, 0);
      c1 = __builtin_amdgcn_mfma_f32_16x16x32_bf16(a1[1], bf1, c1, 0, 0, 0);
      c1 = __builtin_amdgcn_mfma_f32_16x16x32_bf16(a1[2], bf2, c1, 0, 0, 0);
      c1 = __builtin_amdgcn_mfma_f32_16x16x32_bf16(a1[3], bf3, c1, 0, 0, 0);
      int cflat = ct * 16 + lr;
      if (cflat < C2) {
        float bias = b3[cflat];
        int cdiv = cflat / CC;           // magic-mul
        int dd = cflat - cdiv * CC;
#pragma unroll
        for (int r = 0; r < 4; ++r) {
          int jl0 = lg * 4 + r, j = j0 + jl0;
          float v = fmaxf(c0[r] + bias, 0.f);
          if (j == i) v = 0.f;
          out_eij[(i * NN + j) * C2 + cflat] = v;
          *(unsigned short*)(smem + jl0 * ZSTRJ + cdiv * 48 + dd * 2) = (unsigned short)f2bf(v);

          int jl1 = 16 + lg * 4 + r;
          j = j0 + jl1;
          v = fmaxf(c1[r] + bias, 0.f);
          if (j == i) v = 0.f;
          out_eij[(i * NN + j) * C2 + cflat] = v;
          *(unsigned short*)(smem + jl1 * ZSTRJ + cdiv * 48 + dd * 2) = (unsigned short)f2bf(v);
        }
      }
    }
    __syncthreads();

    // ---- phase3: coevolution MFMA (wave w = m-tile w) ----
#pragma unroll 4
    for (int jj = 0; jj < 32; ++jj) {
      int s = msa_s[jj * 128 + w * 16 + lr];
      int rel = s - lg * 8;
      unsigned hval = (s != 21 && ((unsigned)rel) < 8u) ? (0x3F80u << ((rel & 1) << 4)) : 0u;
      int word = rel >> 1;
      union { short8 s8; unsigned u[4]; } bu;
      bu.u[0] = (word == 0) ? hval : 0u;
      bu.u[1] = (word == 1) ? hval : 0u;
      bu.u[2] = (word == 2) ? hval : 0u;
      bu.u[3] = (word == 3) ? hval : 0u;
#pragma unroll
      for (int cp = 0; cp < 2; ++cp) {
        // c>=22 rows of cp=1 read adjacent-j/pad data (finite) -> discarded
        // output rows; d 24..31 overflow hits one-hot zeros (s<=20 => d<=21).
        short8 af = *(const short8*)(smem + jj * ZSTRJ + (cp * 16 + lr) * 48 + lg * 16);
        acc[cp] = __builtin_amdgcn_mfma_f32_16x16x32_bf16(af, bu.s8, acc[cp], 0, 0, 0);
      }
    }
    __syncthreads();   // zE/zln reuse next chunk
  }

  // ---- epilogue: atomicAdd hi (+ ei on jh==0), 2-way per address ----
  {
    int m = w * 16 + lr;
#pragma unroll
    for (int cp = 0; cp < 2; ++cp) {
#pragma unroll
      for (int r = 0; r < 4; ++r) {
        int c = cp * 16 + lg * 4 + r;
        if (c < CC) {
          float add = acc[cp][r] + (jh == 0 ? ei[i * CC + c] : 0.f);
          atomicAdd(&out_log[(m * NN + i) * CC + c], add);
        }
      }
    }
  }
}

// ---------------------------------------------------------------------------
extern "C" void kernel_launch(void* const* d_in, const int* in_sizes, int n_in,
                              void* d_out, int out_size, void* d_ws, size_t ws_size,
                              hipStream_t stream) {
  const float* single = (const float*)d_in[0];
  const float* pairp  = (const float*)d_in[1];
  const int*   msa    = (const int*)d_in[2];
  const float* w1  = (const float*)d_in[3];
  const float* b1  = (const float*)d_in[4];
  const float* g1  = (const float*)d_in[5];
  const float* be1 = (const float*)d_in[6];
  const float* w2  = (const float*)d_in[7];
  const float* b2  = (const float*)d_in[8];
  const float* g2  = (const float*)d_in[9];
  const float* be2 = (const float*)d_in[10];
  const float* w3  = (const float*)d_in[11];
  const float* b3  = (const float*)d_in[12];

  float* out = (float*)d_out;
  float* out_eij = out;
  float* out_ei  = out + OUT_EI;
  float* out_log = out + OUT_LOG;

  int4* w3f = (int4*)d_ws;                                   // 124 KB
  unsigned char* msa_tb = (unsigned char*)d_ws + 131072;     // 32 KB

  hipLaunchKernelGGL(k_prep, dim3(NN), dim3(128), 0, stream, w3, msa, w3f, msa_tb);
  hipLaunchKernelGGL(k_single, dim3(NN), dim3(384), 0, stream,
                     single, w1, b1, g1, be1, w2, b2, out_ei, out_log);
  hipLaunchKernelGGL(k_fused, dim3(256, 2), dim3(512), 0, stream,
                     pairp, msa_tb, g2, be2, b3, (const int4*)w3f,
                     out_ei, out_eij, out_log);
}